// Round 1
// baseline (421.995 us; speedup 1.0000x reference)
//
#include <hip/hip_runtime.h>
#include <math.h>

#define TT 512
#define GG 3
#define HH 32
#define DD 128

__device__ __forceinline__ float fast_sigmoid(float x) {
  float e = __expf(-x);
  return __builtin_amdgcn_rcpf(1.0f + e);
}
__device__ __forceinline__ float fast_tanh(float x) {
  float e = __expf(2.0f * x);
  return 1.0f - 2.0f * __builtin_amdgcn_rcpf(1.0f + e);
}

// One (b,g) sequence per 32-lane half-wave. Lane l owns h[l] and rows
// {l, 32+l, 64+l} of W_hh[g] (96 VGPRs). h-vector is exchanged through LDS
// wave-synchronously (no __syncthreads: each sequence is confined to one wave).
__global__ __launch_bounds__(256) void gru_scan(
    const float* __restrict__ x, const float* __restrict__ W_ih,
    const float* __restrict__ W_hh, const float* __restrict__ b_ih,
    const float* __restrict__ b_hh, float* __restrict__ hout, int B) {
  const int tid = threadIdx.x;
  const int lane = tid & 31;
  const int grp = tid >> 5;                  // 0..7 pair-in-block
  const int p = blockIdx.x * 8 + grp;        // sequence id = b*G + g
  const int b = p / GG, g = p % GG;

  __shared__ float sh_h[8][HH];
  __shared__ float sh_x[8][HH];

  const float* Wg = W_hh + (size_t)g * 3 * HH * HH;
  float wr[HH], wz[HH], wn[HH];
#pragma unroll
  for (int k = 0; k < HH; k += 4) {
    float4 a = *(const float4*)(Wg + (size_t)lane * HH + k);
    float4 c = *(const float4*)(Wg + (size_t)(HH + lane) * HH + k);
    float4 d = *(const float4*)(Wg + (size_t)(2 * HH + lane) * HH + k);
    wr[k] = a.x; wr[k + 1] = a.y; wr[k + 2] = a.z; wr[k + 3] = a.w;
    wz[k] = c.x; wz[k + 1] = c.y; wz[k + 2] = c.z; wz[k + 3] = c.w;
    wn[k] = d.x; wn[k + 1] = d.y; wn[k + 2] = d.z; wn[k + 3] = d.w;
  }
  const float wi_r = W_ih[g * 96 + lane];
  const float wi_z = W_ih[g * 96 + 32 + lane];
  const float wi_n = W_ih[g * 96 + 64 + lane];
  const float br  = b_ih[g * 96 + lane]      + b_hh[g * 96 + lane];
  const float bz  = b_ih[g * 96 + 32 + lane] + b_hh[g * 96 + 32 + lane];
  const float bin = b_ih[g * 96 + 64 + lane];
  const float bhn = b_hh[g * 96 + 64 + lane];

  float hs = 0.0f;
  sh_h[grp][lane] = 0.0f;
  const float* xp = x + ((size_t)b * TT) * GG + g;

#pragma unroll 1
  for (int c = 0; c < TT / 32; ++c) {
    // stage 32 x-scalars for this sequence: lane l loads x[b, c*32+l, g]
    sh_x[grp][lane] = xp[(size_t)(c * 32 + lane) * GG];
    __builtin_amdgcn_wave_barrier();
#pragma unroll
    for (int s = 0; s < 32; ++s) {
      float xv = sh_x[grp][s];               // LDS broadcast
      float dr0 = 0.f, dr1 = 0.f, dz0 = 0.f, dz1 = 0.f, dn0 = 0.f, dn1 = 0.f;
#pragma unroll
      for (int k = 0; k < HH; k += 4) {
        float4 hv = *(const float4*)(&sh_h[grp][k]);  // broadcast b128
        dr0 = fmaf(hv.x, wr[k], dr0);     dr1 = fmaf(hv.y, wr[k + 1], dr1);
        dr0 = fmaf(hv.z, wr[k + 2], dr0); dr1 = fmaf(hv.w, wr[k + 3], dr1);
        dz0 = fmaf(hv.x, wz[k], dz0);     dz1 = fmaf(hv.y, wz[k + 1], dz1);
        dz0 = fmaf(hv.z, wz[k + 2], dz0); dz1 = fmaf(hv.w, wz[k + 3], dz1);
        dn0 = fmaf(hv.x, wn[k], dn0);     dn1 = fmaf(hv.y, wn[k + 1], dn1);
        dn0 = fmaf(hv.z, wn[k + 2], dn0); dn1 = fmaf(hv.w, wn[k + 3], dn1);
      }
      float r = fast_sigmoid(fmaf(xv, wi_r, br) + dr0 + dr1);
      float z = fast_sigmoid(fmaf(xv, wi_z, bz) + dz0 + dz1);
      float n = fast_tanh(fmaf(xv, wi_n, bin) + r * (dn0 + dn1 + bhn));
      hs = fmaf(z, hs - n, n);             // (1-z)*n + z*h
      __builtin_amdgcn_wave_barrier();
      sh_h[grp][lane] = hs;
      __builtin_amdgcn_wave_barrier();
    }
  }
  hout[(size_t)p * HH + lane] = hs;
}

// One block per b: query -> scores -> softmax -> weighted rep -> out row,
// then broadcast-write the row across all T positions (coalesced float4).
__global__ __launch_bounds__(256) void epilogue(
    const float* __restrict__ ctx, const float* __restrict__ hf,
    const float* __restrict__ Wq, const float* __restrict__ bq,
    const float* __restrict__ Ws, const float* __restrict__ bs,
    const float* __restrict__ Wo, const float* __restrict__ bo,
    const float* __restrict__ logT, float* __restrict__ out, int B) {
  const int b = blockIdx.x;
  const int tid = threadIdx.x;
  __shared__ float sc[DD];
  __shared__ float sw[HH];
  __shared__ float srow[DD];
  if (tid < DD) sc[tid] = ctx[(size_t)b * DD + tid];
  __syncthreads();
  if (tid < HH) {
    float q = bq[tid];
#pragma unroll 4
    for (int d = 0; d < DD; ++d) q = fmaf(sc[d], Wq[d * HH + tid], q);
    float h0 = hf[((size_t)b * 3 + 0) * HH + tid];
    float h1 = hf[((size_t)b * 3 + 1) * HH + tid];
    float h2 = hf[((size_t)b * 3 + 2) * HH + tid];
    float wsv = Ws[tid];
    float s0 = fast_tanh(h0 + q) * wsv;
    float s1 = fast_tanh(h1 + q) * wsv;
    float s2 = fast_tanh(h2 + q) * wsv;
#pragma unroll
    for (int off = 16; off >= 1; off >>= 1) {
      s0 += __shfl_xor(s0, off, 32);
      s1 += __shfl_xor(s1, off, 32);
      s2 += __shfl_xor(s2, off, 32);
    }
    float bsv = bs[0];
    float tmp = fmaxf(__expf(logT[0]), 0.1f);
    float inv = 1.0f / tmp;
    s0 = (s0 + bsv) * inv; s1 = (s1 + bsv) * inv; s2 = (s2 + bsv) * inv;
    float m = fmaxf(s0, fmaxf(s1, s2));
    float e0 = __expf(s0 - m), e1 = __expf(s1 - m), e2 = __expf(s2 - m);
    float den = 1.0f / (e0 + e1 + e2);
    float a0 = e0 * den, a1 = e1 * den, a2 = e2 * den;
    sw[tid] = a0 * h0 + a1 * h1 + a2 * h2;
    if (tid == 0) {
      size_t aoff = (size_t)B * TT * DD + (size_t)b * 3;
      out[aoff] = a0; out[aoff + 1] = a1; out[aoff + 2] = a2;
    }
  }
  __syncthreads();
  if (tid < DD) {
    float o = bo[tid];
#pragma unroll
    for (int h = 0; h < HH; ++h) o = fmaf(sw[h], Wo[h * DD + tid], o);
    srow[tid] = o;
  }
  __syncthreads();
  const float4 v = *(const float4*)&srow[(tid & 31) * 4];
  float4* o4 = (float4*)out + (size_t)b * (TT * DD / 4);
#pragma unroll 4
  for (int i = tid; i < TT * DD / 4; i += 256) {
    o4[i] = v;   // i mod 32 == tid mod 32, so v matches column for every i
  }
}

extern "C" void kernel_launch(void* const* d_in, const int* in_sizes, int n_in,
                              void* d_out, int out_size, void* d_ws, size_t ws_size,
                              hipStream_t stream) {
  const float* x    = (const float*)d_in[0];
  const float* ctx  = (const float*)d_in[1];
  const float* W_ih = (const float*)d_in[2];
  const float* W_hh = (const float*)d_in[3];
  const float* b_ih = (const float*)d_in[4];
  const float* b_hh = (const float*)d_in[5];
  const float* Wq   = (const float*)d_in[6];
  const float* bq   = (const float*)d_in[7];
  const float* Ws   = (const float*)d_in[8];
  const float* bs   = (const float*)d_in[9];
  const float* Wo   = (const float*)d_in[10];
  const float* bo   = (const float*)d_in[11];
  const float* logT = (const float*)d_in[12];
  float* out = (float*)d_out;
  const int B = in_sizes[0] / (TT * GG);

  float* hf = (float*)d_ws;  // B*G*H floats = 786 KB

  dim3 g1((B * GG) / 8);
  gru_scan<<<g1, 256, 0, stream>>>(x, W_ih, W_hh, b_ih, b_hh, hf, B);
  epilogue<<<B, 256, 0, stream>>>(ctx, hf, Wq, bq, Ws, bs, Wo, bo, logT, out, B);
}

// Round 3
// 382.150 us; speedup vs baseline: 1.1043x; 1.1043x over previous
//
#include <hip/hip_runtime.h>
#include <math.h>

#define TT 512
#define GG 3
#define HH 32
#define DD 128

typedef _Float16 half8 __attribute__((ext_vector_type(8)));
typedef float f32x4 __attribute__((ext_vector_type(4)));

__device__ __forceinline__ float fast_tanh(float x) {
  float e = __expf(2.0f * x);
  return 1.0f - 2.0f * __builtin_amdgcn_rcpf(1.0f + e);
}

__device__ __forceinline__ uint32_t pack_half2(float a, float b) {
  auto p = __builtin_amdgcn_cvt_pkrtz(a, b);   // __fp16 ext_vector(2)
  return __builtin_bit_cast(uint32_t, p);
}

// 16 sequences (same g) per 64-lane wave. W_hh·h via mfma_f32_16x16x32_f16:
// A = W_hh rows (static, log2e-scaled), B = h (fp16, rebuilt in LDS each step),
// D[j-tile, s]: col=lane&15=s, row=(lane>>4)*4+reg=j. Gates elementwise f32.
__global__ __launch_bounds__(64) void gru_scan_mfma(
    const float* __restrict__ x, const float* __restrict__ W_ih,
    const float* __restrict__ W_hh, const float* __restrict__ b_ih,
    const float* __restrict__ b_hh, float* __restrict__ hout, int B) {
  const int tid = threadIdx.x;
  const int col = tid & 15;   // s for B/C; m-row for A
  const int grp = tid >> 4;   // 0..3 (k-block for A/B, row-group for C)
  const int nb = B / 16;
  const int g = blockIdx.x / nb;
  const int b0 = (blockIdx.x % nb) * 16;
  const float L2E = 1.44269504088896340736f;

  // ---- A fragments: lane holds A[m=col, k=grp*8+i], pre-scaled ----
  // r,z scaled by -log2e (so exp2 gives e^-pre); n scaled by 2*log2e (tanh).
  half8 Af[3][2];
  const float* Wg = W_hh + (size_t)g * 3 * HH * HH;
#pragma unroll
  for (int gam = 0; gam < 3; ++gam) {
    const float sc = (gam == 2) ? 2.0f * L2E : -L2E;
#pragma unroll
    for (int T = 0; T < 2; ++T) {
      const float* src = Wg + (size_t)(gam * 32 + T * 16 + col) * HH + grp * 8;
      half8 a;
#pragma unroll
      for (int i = 0; i < 8; ++i) a[i] = (_Float16)(src[i] * sc);
      Af[gam][T] = a;
    }
  }

  // ---- per-lane gate constants for j = T*16 + grp*4 + r (C layout) ----
  float wiR[2][4], wiZ[2][4], wiN[2][4], bR[2][4], bZ[2][4], bN[2][4], bHN[2][4];
#pragma unroll
  for (int T = 0; T < 2; ++T)
#pragma unroll
    for (int r = 0; r < 4; ++r) {
      int j = T * 16 + grp * 4 + r;
      wiR[T][r] = W_ih[g * 96 + j] * (-L2E);
      wiZ[T][r] = W_ih[g * 96 + 32 + j] * (-L2E);
      wiN[T][r] = W_ih[g * 96 + 64 + j] * (2.0f * L2E);
      bR[T][r] = (b_ih[g * 96 + j] + b_hh[g * 96 + j]) * (-L2E);
      bZ[T][r] = (b_ih[g * 96 + 32 + j] + b_hh[g * 96 + 32 + j]) * (-L2E);
      bN[T][r] = b_ih[g * 96 + 64 + j] * (2.0f * L2E);
      bHN[T][r] = b_hh[g * 96 + 64 + j] * (2.0f * L2E);
    }

  // ---- h state (f32) + fp16 exchange buffer in LDS ----
  // hbuf[s][w]: w = k/2 dword (k = h index as fp16 pair), rows padded to 20.
  __shared__ uint32_t hbuf[16][20];
  float ho[2][4];
#pragma unroll
  for (int T = 0; T < 2; ++T)
#pragma unroll
    for (int r = 0; r < 4; ++r) ho[T][r] = 0.0f;
#pragma unroll
  for (int i = 0; i < 5; ++i) ((uint32_t*)hbuf)[tid + 64 * i] = 0u;

  const float* xp = x + ((size_t)(b0 + col) * TT) * GG + g;
  float xcur = xp[0];

  const f32x4 zero = {0.f, 0.f, 0.f, 0.f};
#pragma unroll 1
  for (int t = 0; t < TT; ++t) {
    int tn1 = (t + 1 < TT) ? (t + 1) : (TT - 1);
    float xnext = xp[(size_t)tn1 * GG];

    // B operand: lane reads h[s=col, k=grp*8 .. +7] (fp16)
    half8 Bf = *(const half8*)&hbuf[col][4 * grp];

    f32x4 Cr0 = __builtin_amdgcn_mfma_f32_16x16x32_f16(Af[0][0], Bf, zero, 0, 0, 0);
    f32x4 Cr1 = __builtin_amdgcn_mfma_f32_16x16x32_f16(Af[0][1], Bf, zero, 0, 0, 0);
    f32x4 Cz0 = __builtin_amdgcn_mfma_f32_16x16x32_f16(Af[1][0], Bf, zero, 0, 0, 0);
    f32x4 Cz1 = __builtin_amdgcn_mfma_f32_16x16x32_f16(Af[1][1], Bf, zero, 0, 0, 0);
    f32x4 Cn0 = __builtin_amdgcn_mfma_f32_16x16x32_f16(Af[2][0], Bf, zero, 0, 0, 0);
    f32x4 Cn1 = __builtin_amdgcn_mfma_f32_16x16x32_f16(Af[2][1], Bf, zero, 0, 0, 0);

#pragma unroll
    for (int T = 0; T < 2; ++T) {
      const f32x4& Cr = T ? Cr1 : Cr0;
      const f32x4& Cz = T ? Cz1 : Cz0;
      const f32x4& Cn = T ? Cn1 : Cn0;
#pragma unroll
      for (int r = 0; r < 4; ++r) {
        // pre-activations already scaled for exp2
        float pr = Cr[r] + fmaf(xcur, wiR[T][r], bR[T][r]);
        float rr = __builtin_amdgcn_rcpf(1.0f + __builtin_amdgcn_exp2f(pr));
        float pz = Cz[r] + fmaf(xcur, wiZ[T][r], bZ[T][r]);
        float zz = __builtin_amdgcn_rcpf(1.0f + __builtin_amdgcn_exp2f(pz));
        float tnv = Cn[r] + bHN[T][r];
        float pn = fmaf(rr, tnv, fmaf(xcur, wiN[T][r], bN[T][r]));
        float u = __builtin_amdgcn_rcpf(1.0f + __builtin_amdgcn_exp2f(pn));
        float nn = fmaf(-2.0f, u, 1.0f);
        float h = ho[T][r];
        ho[T][r] = fmaf(zz, h - nn, nn);
      }
    }

    // pack h_new -> fp16, store into hbuf (k = j): tile T words [T*8+2g, T*8+2g+1]
    uint2 w01, w23;
    w01.x = pack_half2(ho[0][0], ho[0][1]);
    w01.y = pack_half2(ho[0][2], ho[0][3]);
    w23.x = pack_half2(ho[1][0], ho[1][1]);
    w23.y = pack_half2(ho[1][2], ho[1][3]);
    *(uint2*)&hbuf[col][2 * grp] = w01;
    *(uint2*)&hbuf[col][8 + 2 * grp] = w23;

    xcur = xnext;
  }

#pragma unroll
  for (int T = 0; T < 2; ++T)
#pragma unroll
    for (int r = 0; r < 4; ++r) {
      int j = T * 16 + grp * 4 + r;
      hout[((size_t)(b0 + col) * GG + g) * HH + j] = ho[T][r];
    }
}

// One block per b: query -> scores -> softmax -> weighted rep -> out row,
// then broadcast-write the row across all T positions (coalesced float4).
__global__ __launch_bounds__(256) void epilogue(
    const float* __restrict__ ctx, const float* __restrict__ hf,
    const float* __restrict__ Wq, const float* __restrict__ bq,
    const float* __restrict__ Ws, const float* __restrict__ bs,
    const float* __restrict__ Wo, const float* __restrict__ bo,
    const float* __restrict__ logT, float* __restrict__ out, int B) {
  const int b = blockIdx.x;
  const int tid = threadIdx.x;
  __shared__ float sc[DD];
  __shared__ float sw[HH];
  __shared__ float srow[DD];
  if (tid < DD) sc[tid] = ctx[(size_t)b * DD + tid];
  __syncthreads();
  if (tid < HH) {
    float q = bq[tid];
#pragma unroll 4
    for (int d = 0; d < DD; ++d) q = fmaf(sc[d], Wq[d * HH + tid], q);
    float h0 = hf[((size_t)b * 3 + 0) * HH + tid];
    float h1 = hf[((size_t)b * 3 + 1) * HH + tid];
    float h2 = hf[((size_t)b * 3 + 2) * HH + tid];
    float wsv = Ws[tid];
    float s0 = fast_tanh(h0 + q) * wsv;
    float s1 = fast_tanh(h1 + q) * wsv;
    float s2 = fast_tanh(h2 + q) * wsv;
#pragma unroll
    for (int off = 16; off >= 1; off >>= 1) {
      s0 += __shfl_xor(s0, off, 32);
      s1 += __shfl_xor(s1, off, 32);
      s2 += __shfl_xor(s2, off, 32);
    }
    float bsv = bs[0];
    float tmp = fmaxf(__expf(logT[0]), 0.1f);
    float inv = 1.0f / tmp;
    s0 = (s0 + bsv) * inv; s1 = (s1 + bsv) * inv; s2 = (s2 + bsv) * inv;
    float m = fmaxf(s0, fmaxf(s1, s2));
    float e0 = __expf(s0 - m), e1 = __expf(s1 - m), e2 = __expf(s2 - m);
    float den = 1.0f / (e0 + e1 + e2);
    float a0 = e0 * den, a1 = e1 * den, a2 = e2 * den;
    sw[tid] = a0 * h0 + a1 * h1 + a2 * h2;
    if (tid == 0) {
      size_t aoff = (size_t)B * TT * DD + (size_t)b * 3;
      out[aoff] = a0; out[aoff + 1] = a1; out[aoff + 2] = a2;
    }
  }
  __syncthreads();
  if (tid < DD) {
    float o = bo[tid];
#pragma unroll
    for (int h = 0; h < HH; ++h) o = fmaf(sw[h], Wo[h * DD + tid], o);
    srow[tid] = o;
  }
  __syncthreads();
  const float4 v = *(const float4*)&srow[(tid & 31) * 4];
  float4* o4 = (float4*)out + (size_t)b * (TT * DD / 4);
#pragma unroll 4
  for (int i = tid; i < TT * DD / 4; i += 256) {
    o4[i] = v;
  }
}

extern "C" void kernel_launch(void* const* d_in, const int* in_sizes, int n_in,
                              void* d_out, int out_size, void* d_ws, size_t ws_size,
                              hipStream_t stream) {
  const float* x    = (const float*)d_in[0];
  const float* ctx  = (const float*)d_in[1];
  const float* W_ih = (const float*)d_in[2];
  const float* W_hh = (const float*)d_in[3];
  const float* b_ih = (const float*)d_in[4];
  const float* b_hh = (const float*)d_in[5];
  const float* Wq   = (const float*)d_in[6];
  const float* bq   = (const float*)d_in[7];
  const float* Ws   = (const float*)d_in[8];
  const float* bs   = (const float*)d_in[9];
  const float* Wo   = (const float*)d_in[10];
  const float* bo   = (const float*)d_in[11];
  const float* logT = (const float*)d_in[12];
  float* out = (float*)d_out;
  const int B = in_sizes[0] / (TT * GG);

  float* hf = (float*)d_ws;  // B*G*H floats

  dim3 g1((B / 16) * GG);
  gru_scan_mfma<<<g1, 64, 0, stream>>>(x, W_ih, W_hh, b_ih, b_hh, hf, B);
  epilogue<<<B, 256, 0, stream>>>(ctx, hf, Wq, bq, Ws, bs, Wo, bo, logT, out, B);
}

// Round 5
// 341.858 us; speedup vs baseline: 1.2344x; 1.1179x over previous
//
#include <hip/hip_runtime.h>
#include <math.h>

#define TT 512
#define GG 3
#define HH 32
#define DD 128

typedef _Float16 half8 __attribute__((ext_vector_type(8)));
typedef float f32x4 __attribute__((ext_vector_type(4)));

__device__ __forceinline__ float fast_tanh(float x) {
  float e = __expf(2.0f * x);
  return 1.0f - 2.0f * __builtin_amdgcn_rcpf(1.0f + e);
}

__device__ __forceinline__ uint32_t pack_half2(float a, float b) {
  auto p = __builtin_amdgcn_cvt_pkrtz(a, b);   // __fp16 ext_vector(2)
  return __builtin_bit_cast(uint32_t, p);
}

// 16 sequences (same g) per block of 2 waves; wave w owns j-tile [16w,16w+16).
// Per step per wave: 3x mfma_f32_16x16x32_f16 (A = static log2e-scaled W_hh
// rows for its j-tile, B = full h from LDS), 24 transcendentals, write its
// 16-j half of h_new (fp16) into the other LDS buffer, one barrier.
__global__ __launch_bounds__(128) void gru_scan_mfma(
    const float* __restrict__ x, const float* __restrict__ W_ih,
    const float* __restrict__ W_hh, const float* __restrict__ b_ih,
    const float* __restrict__ b_hh, float* __restrict__ hout, int B) {
  const int tid = threadIdx.x;
  const int w = tid >> 6;      // j-tile of this wave
  const int lane = tid & 63;
  const int col = lane & 15;   // seq for B/C; m-row for A
  const int grp = lane >> 4;   // k-block for A/B; row-group for C
  const int nb = B / 16;
  const int g = blockIdx.x / nb;
  const int b0 = (blockIdx.x % nb) * 16;
  const float L2E = 1.44269504088896340736f;

  // ---- A fragments for this wave's j-tile (pre-scaled for exp2) ----
  half8 Af[3];
  const float* Wg = W_hh + (size_t)g * 3 * HH * HH;
#pragma unroll
  for (int gam = 0; gam < 3; ++gam) {
    const float sc = (gam == 2) ? 2.0f * L2E : -L2E;
    const float* src = Wg + (size_t)(gam * 32 + w * 16 + col) * HH + grp * 8;
    half8 a;
#pragma unroll
    for (int i = 0; i < 8; ++i) a[i] = (_Float16)(src[i] * sc);
    Af[gam] = a;
  }

  // ---- per-lane gate constants for j = w*16 + grp*4 + r ----
  float wiR[4], wiZ[4], wiN[4], bR[4], bZ[4], bN[4], bHN[4];
#pragma unroll
  for (int r = 0; r < 4; ++r) {
    int j = w * 16 + grp * 4 + r;
    wiR[r] = W_ih[g * 96 + j] * (-L2E);
    wiZ[r] = W_ih[g * 96 + 32 + j] * (-L2E);
    wiN[r] = W_ih[g * 96 + 64 + j] * (2.0f * L2E);
    bR[r] = (b_ih[g * 96 + j] + b_hh[g * 96 + j]) * (-L2E);
    bZ[r] = (b_ih[g * 96 + 32 + j] + b_hh[g * 96 + 32 + j]) * (-L2E);
    bN[r] = b_ih[g * 96 + 64 + j] * (2.0f * L2E);
    bHN[r] = b_hh[g * 96 + 64 + j] * (2.0f * L2E);
  }

  // ---- double-buffered fp16 h in LDS: [buf][seq][16 words + 4 pad] ----
  __shared__ uint32_t hbuf[2][16][20];
  float ho[4];
#pragma unroll
  for (int r = 0; r < 4; ++r) ho[r] = 0.0f;
  for (int i = tid; i < 320; i += 128) ((uint32_t*)hbuf)[i] = 0u;  // zero buf 0
  __syncthreads();

  const float* xp = x + ((size_t)(b0 + col) * TT) * GG + g;
  float xcur = xp[0];
  const f32x4 zero = {0.f, 0.f, 0.f, 0.f};

#define GRU_STEP(SRC, DST, TNEXT)                                              \
  {                                                                            \
    float xnext = xp[(size_t)(TNEXT)*GG];                                      \
    half8 Bf = *(const half8*)&hbuf[SRC][col][grp * 4];                        \
    f32x4 Cr = __builtin_amdgcn_mfma_f32_16x16x32_f16(Af[0], Bf, zero, 0, 0, 0); \
    f32x4 Cz = __builtin_amdgcn_mfma_f32_16x16x32_f16(Af[1], Bf, zero, 0, 0, 0); \
    f32x4 Cn = __builtin_amdgcn_mfma_f32_16x16x32_f16(Af[2], Bf, zero, 0, 0, 0); \
    _Pragma("unroll") for (int r = 0; r < 4; ++r) {                            \
      float pr = Cr[r] + fmaf(xcur, wiR[r], bR[r]);                            \
      float rr = __builtin_amdgcn_rcpf(1.0f + __builtin_amdgcn_exp2f(pr));     \
      float pz = Cz[r] + fmaf(xcur, wiZ[r], bZ[r]);                            \
      float zz = __builtin_amdgcn_rcpf(1.0f + __builtin_amdgcn_exp2f(pz));     \
      float tnv = Cn[r] + bHN[r];                                              \
      float pn = fmaf(rr, tnv, fmaf(xcur, wiN[r], bN[r]));                     \
      float u = __builtin_amdgcn_rcpf(1.0f + __builtin_amdgcn_exp2f(pn));      \
      float nn = fmaf(-2.0f, u, 1.0f);                                        \
      ho[r] = fmaf(zz, ho[r] - nn, nn);                                        \
    }                                                                          \
    uint2 wpk;                                                                 \
    wpk.x = pack_half2(ho[0], ho[1]);                                          \
    wpk.y = pack_half2(ho[2], ho[3]);                                          \
    *(uint2*)&hbuf[DST][col][w * 8 + grp * 2] = wpk;                           \
    __syncthreads();                                                           \
    xcur = xnext;                                                              \
  }

#pragma unroll 1
  for (int t = 0; t < TT; t += 2) {
    GRU_STEP(0, 1, t + 1)
    GRU_STEP(1, 0, (t + 2 < TT) ? (t + 2) : (TT - 1))
  }
#undef GRU_STEP

#pragma unroll
  for (int r = 0; r < 4; ++r) {
    int j = w * 16 + grp * 4 + r;
    hout[((size_t)(b0 + col) * GG + g) * HH + j] = ho[r];
  }
}

// One block per b: query -> scores -> softmax -> weighted rep -> out row,
// then broadcast-write the row across all T positions (coalesced float4).
__global__ __launch_bounds__(256) void epilogue(
    const float* __restrict__ ctx, const float* __restrict__ hf,
    const float* __restrict__ Wq, const float* __restrict__ bq,
    const float* __restrict__ Ws, const float* __restrict__ bs,
    const float* __restrict__ Wo, const float* __restrict__ bo,
    const float* __restrict__ logT, float* __restrict__ out, int B) {
  const int b = blockIdx.x;
  const int tid = threadIdx.x;
  __shared__ float sc[DD];
  __shared__ float sw[HH];
  __shared__ float srow[DD];
  if (tid < DD) sc[tid] = ctx[(size_t)b * DD + tid];
  __syncthreads();
  if (tid < HH) {
    float q = bq[tid];
#pragma unroll 4
    for (int d = 0; d < DD; ++d) q = fmaf(sc[d], Wq[d * HH + tid], q);
    float h0 = hf[((size_t)b * 3 + 0) * HH + tid];
    float h1 = hf[((size_t)b * 3 + 1) * HH + tid];
    float h2 = hf[((size_t)b * 3 + 2) * HH + tid];
    float wsv = Ws[tid];
    float s0 = fast_tanh(h0 + q) * wsv;
    float s1 = fast_tanh(h1 + q) * wsv;
    float s2 = fast_tanh(h2 + q) * wsv;
#pragma unroll
    for (int off = 16; off >= 1; off >>= 1) {
      s0 += __shfl_xor(s0, off, 32);
      s1 += __shfl_xor(s1, off, 32);
      s2 += __shfl_xor(s2, off, 32);
    }
    float bsv = bs[0];
    float tmp = fmaxf(__expf(logT[0]), 0.1f);
    float inv = 1.0f / tmp;
    s0 = (s0 + bsv) * inv; s1 = (s1 + bsv) * inv; s2 = (s2 + bsv) * inv;
    float m = fmaxf(s0, fmaxf(s1, s2));
    float e0 = __expf(s0 - m), e1 = __expf(s1 - m), e2 = __expf(s2 - m);
    float den = 1.0f / (e0 + e1 + e2);
    float a0 = e0 * den, a1 = e1 * den, a2 = e2 * den;
    sw[tid] = a0 * h0 + a1 * h1 + a2 * h2;
    if (tid == 0) {
      size_t aoff = (size_t)B * TT * DD + (size_t)b * 3;
      out[aoff] = a0; out[aoff + 1] = a1; out[aoff + 2] = a2;
    }
  }
  __syncthreads();
  if (tid < DD) {
    float o = bo[tid];
#pragma unroll
    for (int h = 0; h < HH; ++h) o = fmaf(sw[h], Wo[h * DD + tid], o);
    srow[tid] = o;
  }
  __syncthreads();
  const float4 v = *(const float4*)&srow[(tid & 31) * 4];
  float4* o4 = (float4*)out + (size_t)b * (TT * DD / 4);
#pragma unroll 4
  for (int i = tid; i < TT * DD / 4; i += 256) {
    o4[i] = v;
  }
}

extern "C" void kernel_launch(void* const* d_in, const int* in_sizes, int n_in,
                              void* d_out, int out_size, void* d_ws, size_t ws_size,
                              hipStream_t stream) {
  const float* x    = (const float*)d_in[0];
  const float* ctx  = (const float*)d_in[1];
  const float* W_ih = (const float*)d_in[2];
  const float* W_hh = (const float*)d_in[3];
  const float* b_ih = (const float*)d_in[4];
  const float* b_hh = (const float*)d_in[5];
  const float* Wq   = (const float*)d_in[6];
  const float* bq   = (const float*)d_in[7];
  const float* Ws   = (const float*)d_in[8];
  const float* bs   = (const float*)d_in[9];
  const float* Wo   = (const float*)d_in[10];
  const float* bo   = (const float*)d_in[11];
  const float* logT = (const float*)d_in[12];
  float* out = (float*)d_out;
  const int B = in_sizes[0] / (TT * GG);

  float* hf = (float*)d_ws;  // B*G*H floats

  dim3 g1((B / 16) * GG);
  gru_scan_mfma<<<g1, 128, 0, stream>>>(x, W_ih, W_hh, b_ih, b_hh, hf, B);
  epilogue<<<B, 256, 0, stream>>>(ctx, hf, Wq, bq, Ws, bs, Wo, bo, logT, out, B);
}